// Round 2
// baseline (1462.928 us; speedup 1.0000x reference)
//
#include <hip/hip_runtime.h>

#define F_IN 256
#define H_DIM 128

// ---------------- K2: degree accumulation (edges only; self-loop folded later)
__global__ __launch_bounds__(256) void deg_kernel(const int* __restrict__ ei,
                                                  const float* __restrict__ ew,
                                                  float* __restrict__ deg, int E) {
    int e = blockIdx.x * blockDim.x + threadIdx.x;
    if (e < E) {
        int d = ei[(size_t)E + e];
        atomicAdd(&deg[d], ew[e]);
    }
}

// ---------------- K3: dinv = rsqrt(deg + 1)  (self-loop weight 1)
__global__ __launch_bounds__(256) void dinv_kernel(float* __restrict__ deg, int N) {
    int i = blockIdx.x * blockDim.x + threadIdx.x;
    if (i < N) {
        deg[i] = rsqrtf(deg[i] + 1.0f);
    }
}

// ---------------- K4: xs = (x @ W^T) * dinv[row];  h = xs * dinv[row] (self-loop msg)
#define BM 64
#define BN 64
#define KC 32
__global__ __launch_bounds__(256) void gemm_kernel(const float* __restrict__ x,
                                                   const float* __restrict__ W,
                                                   const float* __restrict__ dinv,
                                                   float* __restrict__ xs,
                                                   float* __restrict__ h, int N) {
    __shared__ float xT[KC][BM + 4];  // [k][row], pad keeps float4 alignment
    __shared__ float wT[KC][BN + 4];  // [k][col]
    const int tid = threadIdx.x;
    const int tc = tid & 15;          // 0..15 col-group
    const int tr = tid >> 4;          // 0..15 row-group
    const int block_row = blockIdx.x * BM;
    const int block_col = blockIdx.y * BN;   // 0 or 64

    float acc[4][4] = {};

    const int lk = tid & 31;   // k within chunk
    const int lr = tid >> 5;   // base row (0..7)

    for (int kc = 0; kc < F_IN; kc += KC) {
#pragma unroll
        for (int i = 0; i < 8; i++) {
            int r = lr + i * 8;
            int gr = block_row + r;
            float v = (gr < N) ? x[(size_t)gr * F_IN + kc + lk] : 0.0f;
            xT[lk][r] = v;
            float wv = W[(size_t)(block_col + r) * F_IN + kc + lk];
            wT[lk][r] = wv;
        }
        __syncthreads();
#pragma unroll
        for (int k = 0; k < KC; k++) {
            float4 a = *(const float4*)&xT[k][tr * 4];
            float4 b = *(const float4*)&wT[k][tc * 4];
            acc[0][0] += a.x * b.x; acc[0][1] += a.x * b.y; acc[0][2] += a.x * b.z; acc[0][3] += a.x * b.w;
            acc[1][0] += a.y * b.x; acc[1][1] += a.y * b.y; acc[1][2] += a.y * b.z; acc[1][3] += a.y * b.w;
            acc[2][0] += a.z * b.x; acc[2][1] += a.z * b.y; acc[2][2] += a.z * b.z; acc[2][3] += a.z * b.w;
            acc[3][0] += a.w * b.x; acc[3][1] += a.w * b.y; acc[3][2] += a.w * b.z; acc[3][3] += a.w * b.w;
        }
        __syncthreads();
    }

#pragma unroll
    for (int i = 0; i < 4; i++) {
        int gr = block_row + tr * 4 + i;
        if (gr < N) {
            float di = dinv[gr];
            float4 v;
            v.x = acc[i][0] * di; v.y = acc[i][1] * di;
            v.z = acc[i][2] * di; v.w = acc[i][3] * di;
            size_t off = (size_t)gr * H_DIM + block_col + tc * 4;
            *(float4*)&xs[off] = v;
            float4 hv;
            hv.x = v.x * di; hv.y = v.y * di; hv.z = v.z * di; hv.w = v.w * di;
            *(float4*)&h[off] = hv;
        }
    }
}

// ---------------- K5: scatter-add messages. 32 lanes per edge, float4 per lane.
__global__ __launch_bounds__(256) void scatter_kernel(const int* __restrict__ ei,
                                                      const float* __restrict__ ew,
                                                      const float* __restrict__ dinv,
                                                      const float* __restrict__ xs,
                                                      float* __restrict__ h, int E) {
    int t = blockIdx.x * blockDim.x + threadIdx.x;
    int e = t >> 5;
    int f4 = t & 31;
    if (e >= E) return;
    int s = ei[e];
    int d = ei[(size_t)E + e];
    float coef = ew[e] * dinv[d];
    float4 v = ((const float4*)xs)[(size_t)s * 32 + f4];
    float* hp = &h[(size_t)d * H_DIM + f4 * 4];
    atomicAdd(hp + 0, v.x * coef);
    atomicAdd(hp + 1, v.y * coef);
    atomicAdd(hp + 2, v.z * coef);
    atomicAdd(hp + 3, v.w * coef);
}

// ---------------- K6: out = sigmoid(relu(h + b) @ W_lin^T + b_lin)
__global__ __launch_bounds__(256) void out_kernel(const float* __restrict__ h,
                                                  const float* __restrict__ b,
                                                  const float* __restrict__ Wl,
                                                  const float* __restrict__ bl,
                                                  float* __restrict__ out, int N) {
    int i = blockIdx.x * blockDim.x + threadIdx.x;
    if (i >= N) return;
    float z0 = bl[0], z1 = bl[1];
    const float4* h4 = (const float4*)(h + (size_t)i * H_DIM);
    const float4* b4 = (const float4*)b;
    const float4* w0 = (const float4*)Wl;
    const float4* w1 = (const float4*)(Wl + H_DIM);
#pragma unroll
    for (int k = 0; k < H_DIM / 4; k++) {
        float4 v = h4[k];
        float4 bb = b4[k];
        float4 a0 = w0[k];
        float4 a1 = w1[k];
        float r0 = fmaxf(v.x + bb.x, 0.0f);
        float r1 = fmaxf(v.y + bb.y, 0.0f);
        float r2 = fmaxf(v.z + bb.z, 0.0f);
        float r3 = fmaxf(v.w + bb.w, 0.0f);
        z0 += r0 * a0.x + r1 * a0.y + r2 * a0.z + r3 * a0.w;
        z1 += r0 * a1.x + r1 * a1.y + r2 * a1.z + r3 * a1.w;
    }
    out[(size_t)i * 2 + 0] = 1.0f / (1.0f + expf(-z0));
    out[(size_t)i * 2 + 1] = 1.0f / (1.0f + expf(-z1));
}

extern "C" void kernel_launch(void* const* d_in, const int* in_sizes, int n_in,
                              void* d_out, int out_size, void* d_ws, size_t ws_size,
                              hipStream_t stream) {
    const float* x   = (const float*)d_in[0];
    const int* ei    = (const int*)d_in[1];    // int inputs are int32 on device
    const float* ew  = (const float*)d_in[2];
    const float* W   = (const float*)d_in[3];
    const float* b   = (const float*)d_in[4];
    const float* Wl  = (const float*)d_in[5];
    const float* bl  = (const float*)d_in[6];
    float* out = (float*)d_out;

    const int N = in_sizes[0] / F_IN;   // 50000
    const int E = in_sizes[2];          // 800000

    char* ws = (char*)d_ws;
    const size_t h_bytes = (size_t)N * H_DIM * sizeof(float);   // 25.6 MB
    float* xs   = (float*)ws;                       // [N,128]
    float* h    = (float*)(ws + h_bytes);           // [N,128]
    float* dinv = (float*)(ws + 2 * h_bytes);       // [N]

    // deg accumulate -> dinv
    hipMemsetAsync(dinv, 0, (size_t)N * sizeof(float), stream);
    deg_kernel<<<(E + 255) / 256, 256, 0, stream>>>(ei, ew, dinv, E);
    dinv_kernel<<<(N + 255) / 256, 256, 0, stream>>>(dinv, N);

    // xs = (x@W.T)*dinv ; h = self-loop init
    dim3 ggrid((N + BM - 1) / BM, H_DIM / BN);
    gemm_kernel<<<ggrid, 256, 0, stream>>>(x, W, dinv, xs, h, N);

    // edge scatter
    long long tthreads = (long long)E * 32;
    scatter_kernel<<<(int)((tthreads + 255) / 256), 256, 0, stream>>>(ei, ew, dinv, xs, h, E);

    // final linear + sigmoid
    out_kernel<<<(N + 255) / 256, 256, 0, stream>>>(h, b, Wl, bl, out, N);
}

// Round 3
// 336.652 us; speedup vs baseline: 4.3455x; 4.3455x over previous
//
#include <hip/hip_runtime.h>

#define F_IN 256
#define H_DIM 128

// ---------------- K1: per-edge: accumulate weighted degree (f32) + edge count (int) at dst
__global__ __launch_bounds__(256) void deg_count_kernel(const int* __restrict__ ei,
                                                        const float* __restrict__ ew,
                                                        float* __restrict__ deg,
                                                        int* __restrict__ count, int E) {
    int e = blockIdx.x * blockDim.x + threadIdx.x;
    if (e < E) {
        int d = ei[(size_t)E + e];
        atomicAdd(&deg[d], ew[e]);
        atomicAdd(&count[d], 1);
    }
}

// ---------------- K2: dinv = rsqrt(deg + 1)  (self-loop weight 1)
__global__ __launch_bounds__(256) void dinv_kernel(float* __restrict__ deg, int N) {
    int i = blockIdx.x * blockDim.x + threadIdx.x;
    if (i < N) {
        deg[i] = rsqrtf(deg[i] + 1.0f);
    }
}

// ---------------- K3: single-block exclusive scan of count -> start, cursor
__global__ __launch_bounds__(1024) void scan_kernel(const int* __restrict__ count,
                                                    int* __restrict__ start,
                                                    int* __restrict__ cursor, int N) {
    __shared__ int wsum[16];
    __shared__ int wincl[16];
    __shared__ int carry;
    const int tid = threadIdx.x;
    const int lane = tid & 63;
    const int w = tid >> 6;
    if (tid == 0) carry = 0;
    __syncthreads();
    for (int base = 0; base < N; base += 1024) {
        int i = base + tid;
        int v = (i < N) ? count[i] : 0;
        // inclusive wave scan of v
        int s = v;
#pragma unroll
        for (int off = 1; off < 64; off <<= 1) {
            int t = __shfl_up(s, off, 64);
            if (lane >= off) s += t;
        }
        if (lane == 63) wsum[w] = s;
        __syncthreads();
        if (w == 0) {
            int ws = (lane < 16) ? wsum[lane] : 0;
#pragma unroll
            for (int off = 1; off < 16; off <<= 1) {
                int t = __shfl_up(ws, off, 64);
                if (lane >= off) ws += t;
            }
            if (lane < 16) wincl[lane] = ws;
        }
        __syncthreads();
        int woffset = (w > 0) ? wincl[w - 1] : 0;
        int incl = s + woffset + carry;   // inclusive global prefix
        int excl = incl - v;
        if (i < N) { start[i] = excl; cursor[i] = excl; }
        __syncthreads();
        if (tid == 1023) carry = incl;    // incl already contains old carry
        __syncthreads();
    }
}

// ---------------- K4: bucket edges by dst: (src, w) into sorted slots
__global__ __launch_bounds__(256) void place_kernel(const int* __restrict__ ei,
                                                    const float* __restrict__ ew,
                                                    int* __restrict__ cursor,
                                                    int* __restrict__ ssrc,
                                                    float* __restrict__ sw, int E) {
    int e = blockIdx.x * blockDim.x + threadIdx.x;
    if (e < E) {
        int s = ei[e];
        int d = ei[(size_t)E + e];
        int pos = atomicAdd(&cursor[d], 1);
        ssrc[pos] = s;
        sw[pos] = ew[e];
    }
}

// ---------------- K5: xs = (x @ W^T) * dinv[row]
#define BM 64
#define BN 64
#define KC 32
__global__ __launch_bounds__(256) void gemm_kernel(const float* __restrict__ x,
                                                   const float* __restrict__ W,
                                                   const float* __restrict__ dinv,
                                                   float* __restrict__ xs, int N) {
    __shared__ float xT[KC][BM + 4];
    __shared__ float wT[KC][BN + 4];
    const int tid = threadIdx.x;
    const int tc = tid & 15;
    const int tr = tid >> 4;
    const int block_row = blockIdx.x * BM;
    const int block_col = blockIdx.y * BN;

    float acc[4][4] = {};
    const int lk = tid & 31;
    const int lr = tid >> 5;

    for (int kc = 0; kc < F_IN; kc += KC) {
#pragma unroll
        for (int i = 0; i < 8; i++) {
            int r = lr + i * 8;
            int gr = block_row + r;
            xT[lk][r] = (gr < N) ? x[(size_t)gr * F_IN + kc + lk] : 0.0f;
            wT[lk][r] = W[(size_t)(block_col + r) * F_IN + kc + lk];
        }
        __syncthreads();
#pragma unroll
        for (int k = 0; k < KC; k++) {
            float4 a = *(const float4*)&xT[k][tr * 4];
            float4 b = *(const float4*)&wT[k][tc * 4];
            acc[0][0] += a.x * b.x; acc[0][1] += a.x * b.y; acc[0][2] += a.x * b.z; acc[0][3] += a.x * b.w;
            acc[1][0] += a.y * b.x; acc[1][1] += a.y * b.y; acc[1][2] += a.y * b.z; acc[1][3] += a.y * b.w;
            acc[2][0] += a.z * b.x; acc[2][1] += a.z * b.y; acc[2][2] += a.z * b.z; acc[2][3] += a.z * b.w;
            acc[3][0] += a.w * b.x; acc[3][1] += a.w * b.y; acc[3][2] += a.w * b.z; acc[3][3] += a.w * b.w;
        }
        __syncthreads();
    }

#pragma unroll
    for (int i = 0; i < 4; i++) {
        int gr = block_row + tr * 4 + i;
        if (gr < N) {
            float di = dinv[gr];
            float4 v;
            v.x = acc[i][0] * di; v.y = acc[i][1] * di;
            v.z = acc[i][2] * di; v.w = acc[i][3] * di;
            *(float4*)&xs[(size_t)gr * H_DIM + block_col + tc * 4] = v;
        }
    }
}

// ---------------- K6: one wave per dst row: gather-reduce + bias+relu+linear+sigmoid
__global__ __launch_bounds__(256) void gather_out_kernel(const int* __restrict__ start,
                                                         const int* __restrict__ ssrc,
                                                         const float* __restrict__ sw,
                                                         const float* __restrict__ xs,
                                                         const float* __restrict__ dinv,
                                                         const float* __restrict__ b,
                                                         const float* __restrict__ Wl,
                                                         const float* __restrict__ bl,
                                                         float* __restrict__ out,
                                                         int N, int E) {
    int gw = (blockIdx.x * blockDim.x + threadIdx.x) >> 6;  // one wave per row
    int lane = threadIdx.x & 63;
    if (gw >= N) return;
    int s0 = start[gw];
    int s1 = (gw + 1 < N) ? start[gw + 1] : E;

    // self-loop: xs[gw] (already scaled by dinv[gw] as "src")
    float2 acc = ((const float2*)xs)[(size_t)gw * 64 + lane];
    for (int j = s0; j < s1; j++) {
        int src = ssrc[j];
        float wt = sw[j];
        float2 v = ((const float2*)xs)[(size_t)src * 64 + lane];
        acc.x += wt * v.x;
        acc.y += wt * v.y;
    }
    float di = dinv[gw];
    float2 bb = ((const float2*)b)[lane];
    float r0 = fmaxf(acc.x * di + bb.x, 0.0f);
    float r1 = fmaxf(acc.y * di + bb.y, 0.0f);
    float2 w0 = ((const float2*)Wl)[lane];
    float2 w1 = ((const float2*)(Wl + H_DIM))[lane];
    float z0 = r0 * w0.x + r1 * w0.y;
    float z1 = r0 * w1.x + r1 * w1.y;
#pragma unroll
    for (int off = 32; off; off >>= 1) {
        z0 += __shfl_xor(z0, off, 64);
        z1 += __shfl_xor(z1, off, 64);
    }
    if (lane == 0) {
        float2 o;
        o.x = 1.0f / (1.0f + expf(-(z0 + bl[0])));
        o.y = 1.0f / (1.0f + expf(-(z1 + bl[1])));
        ((float2*)out)[gw] = o;
    }
}

extern "C" void kernel_launch(void* const* d_in, const int* in_sizes, int n_in,
                              void* d_out, int out_size, void* d_ws, size_t ws_size,
                              hipStream_t stream) {
    const float* x  = (const float*)d_in[0];
    const int* ei   = (const int*)d_in[1];   // int inputs are int32 on device
    const float* ew = (const float*)d_in[2];
    const float* W  = (const float*)d_in[3];
    const float* b  = (const float*)d_in[4];
    const float* Wl = (const float*)d_in[5];
    const float* bl = (const float*)d_in[6];
    float* out = (float*)d_out;

    const int N = in_sizes[0] / F_IN;   // 50000
    const int E = in_sizes[2];          // 800000

    char* ws = (char*)d_ws;
    size_t off = 0;
    float* xs   = (float*)(ws + off); off += (size_t)N * H_DIM * sizeof(float);  // 25.6 MB
    float* deg  = (float*)(ws + off); off += (size_t)N * sizeof(float);          // dinv in-place
    int* count  = (int*)(ws + off);   off += (size_t)N * sizeof(int);
    int* start  = (int*)(ws + off);   off += (size_t)N * sizeof(int);
    int* cursor = (int*)(ws + off);   off += (size_t)N * sizeof(int);
    int* ssrc   = (int*)(ws + off);   off += (size_t)E * sizeof(int);            // 3.2 MB
    float* sw   = (float*)(ws + off); off += (size_t)E * sizeof(float);          // 3.2 MB

    // zero deg + count (adjacent regions)
    hipMemsetAsync(deg, 0, (size_t)N * (sizeof(float) + sizeof(int)), stream);

    deg_count_kernel<<<(E + 255) / 256, 256, 0, stream>>>(ei, ew, deg, count, E);
    dinv_kernel<<<(N + 255) / 256, 256, 0, stream>>>(deg, N);
    scan_kernel<<<1, 1024, 0, stream>>>(count, start, cursor, N);
    place_kernel<<<(E + 255) / 256, 256, 0, stream>>>(ei, ew, cursor, ssrc, sw, E);

    dim3 ggrid((N + BM - 1) / BM, H_DIM / BN);
    gemm_kernel<<<ggrid, 256, 0, stream>>>(x, W, deg, xs, N);

    long long gthreads = (long long)N * 64;
    gather_out_kernel<<<(int)((gthreads + 255) / 256), 256, 0, stream>>>(
        start, ssrc, sw, xs, deg, b, Wl, bl, out, N, E);
}

// Round 4
// 195.197 us; speedup vs baseline: 7.4946x; 1.7247x over previous
//
#include <hip/hip_runtime.h>

#define F_IN 256
#define H_DIM 128

typedef short bf16x8 __attribute__((ext_vector_type(8)));
typedef float f32x4 __attribute__((ext_vector_type(4)));
typedef unsigned short ushort8 __attribute__((ext_vector_type(8)));

__device__ inline unsigned short f2bf(float f) {
    unsigned int u = __float_as_uint(f);
    u += 0x7fffu + ((u >> 16) & 1u);   // RNE
    return (unsigned short)(u >> 16);
}
__device__ inline float bf_lo(unsigned int u) { return __uint_as_float(u << 16); }
__device__ inline float bf_hi(unsigned int u) { return __uint_as_float(u & 0xffff0000u); }

// ---------------- deg (f32 atomic) + count (int atomic) at dst
__global__ __launch_bounds__(256) void deg_count_kernel(const int* __restrict__ ei,
                                                        const float* __restrict__ ew,
                                                        float* __restrict__ deg,
                                                        int* __restrict__ count, int E) {
    int e = blockIdx.x * blockDim.x + threadIdx.x;
    if (e < E) {
        int d = ei[(size_t)E + e];
        atomicAdd(&deg[d], ew[e]);
        atomicAdd(&count[d], 1);
    }
}

__global__ __launch_bounds__(256) void dinv_kernel(float* __restrict__ deg, int N) {
    int i = blockIdx.x * blockDim.x + threadIdx.x;
    if (i < N) deg[i] = rsqrtf(deg[i] + 1.0f);
}

// ---------------- hierarchical scan: block sums
__global__ __launch_bounds__(256) void block_sum_kernel(const int* __restrict__ count,
                                                        int* __restrict__ bsum, int N) {
    __shared__ int ws[4];
    int tid = threadIdx.x, lane = tid & 63, w = tid >> 6;
    int i = blockIdx.x * 256 + tid;
    int v = (i < N) ? count[i] : 0;
#pragma unroll
    for (int off = 32; off; off >>= 1) v += __shfl_xor(v, off, 64);
    if (lane == 0) ws[w] = v;
    __syncthreads();
    if (tid == 0) bsum[blockIdx.x] = ws[0] + ws[1] + ws[2] + ws[3];
}

// ---------------- scan the (<=256) block sums in-place -> exclusive offsets
__global__ __launch_bounds__(256) void scan_bsum_kernel(int* __restrict__ bsum, int nb) {
    __shared__ int tmp[256];
    int tid = threadIdx.x;
    int orig = (tid < nb) ? bsum[tid] : 0;
    tmp[tid] = orig;
    __syncthreads();
    for (int off = 1; off < 256; off <<= 1) {
        int t = (tid >= off) ? tmp[tid - off] : 0;
        __syncthreads();
        tmp[tid] += t;
        __syncthreads();
    }
    if (tid < nb) bsum[tid] = tmp[tid] - orig;   // exclusive
}

// ---------------- per-block exclusive scan + block offset -> start, cursor
__global__ __launch_bounds__(256) void scan_write_kernel(const int* __restrict__ count,
                                                         const int* __restrict__ bsum,
                                                         int* __restrict__ start,
                                                         int* __restrict__ cursor, int N) {
    __shared__ int ws[4];
    int tid = threadIdx.x, lane = tid & 63, w = tid >> 6;
    int i = blockIdx.x * 256 + tid;
    int v = (i < N) ? count[i] : 0;
    int s = v;
#pragma unroll
    for (int off = 1; off < 64; off <<= 1) {
        int t = __shfl_up(s, off, 64);
        if (lane >= off) s += t;
    }
    if (lane == 63) ws[w] = s;
    __syncthreads();
    int add = bsum[blockIdx.x];
    for (int k = 0; k < w; k++) add += ws[k];
    int excl = s - v + add;
    if (i < N) { start[i] = excl; cursor[i] = excl; }
}

// ---------------- bucket edges by dst: packed (src, w_bits)
__global__ __launch_bounds__(256) void place_kernel(const int* __restrict__ ei,
                                                    const float* __restrict__ ew,
                                                    int* __restrict__ cursor,
                                                    int2* __restrict__ sedge, int E) {
    int e = blockIdx.x * blockDim.x + threadIdx.x;
    if (e < E) {
        int s = ei[e];
        int d = ei[(size_t)E + e];
        int pos = atomicAdd(&cursor[d], 1);
        int2 p; p.x = s; p.y = __float_as_int(ew[e]);
        sedge[pos] = p;
    }
}

// ---------------- W -> bf16
__global__ __launch_bounds__(256) void convw_kernel(const float* __restrict__ W,
                                                    unsigned short* __restrict__ Wb, int n) {
    int i = blockIdx.x * blockDim.x + threadIdx.x;
    if (i < n) Wb[i] = f2bf(W[i]);
}

// ---------------- MFMA GEMM: xs(bf16) = (x @ W^T) * dinv[row]
// block: 256 threads = 4 waves; tile 64(M) x 128(N); K-steps of 64.
__global__ __launch_bounds__(256) void gemm_mfma_kernel(const float* __restrict__ x,
                                                        const unsigned short* __restrict__ Wb,
                                                        const float* __restrict__ dinv,
                                                        unsigned short* __restrict__ xs, int N) {
    __shared__ unsigned short As[64 * 64];    // [row][64 k] bf16, 16B slots XOR-swizzled
    __shared__ unsigned short Bs[128 * 64];   // [col][64 k] bf16
    __shared__ float sdinv[64];
    const int tid = threadIdx.x;
    const int wv = tid >> 6, lane = tid & 63;
    const int block_row = blockIdx.x * 64;
    if (tid < 64) {
        int gr = block_row + tid;
        sdinv[tid] = (gr < N) ? dinv[gr] : 0.0f;
    }
    f32x4 acc[8] = {};

    for (int ks = 0; ks < 4; ks++) {
        // stage A: 64 rows x 8 granules (8 bf16 = 16B each)
#pragma unroll
        for (int it = 0; it < 2; it++) {
            int gg = it * 256 + tid;
            int row = gg >> 3, g = gg & 7;
            int gr = block_row + row;
            float4 v0 = {0, 0, 0, 0}, v1 = {0, 0, 0, 0};
            if (gr < N) {
                const float4* p = (const float4*)&x[(size_t)gr * F_IN + ks * 64 + g * 8];
                v0 = p[0]; v1 = p[1];
            }
            ushort8 o;
            o[0] = f2bf(v0.x); o[1] = f2bf(v0.y); o[2] = f2bf(v0.z); o[3] = f2bf(v0.w);
            o[4] = f2bf(v1.x); o[5] = f2bf(v1.y); o[6] = f2bf(v1.z); o[7] = f2bf(v1.w);
            int slot = g ^ (row & 7);
            *(ushort8*)&As[row * 64 + slot * 8] = o;
        }
        // stage B: 128 cols x 8 granules
#pragma unroll
        for (int it = 0; it < 4; it++) {
            int gg = it * 256 + tid;
            int col = gg >> 3, g = gg & 7;
            ushort8 v = *(const ushort8*)&Wb[(size_t)col * F_IN + ks * 64 + g * 8];
            int slot = g ^ (col & 7);
            *(ushort8*)&Bs[col * 64 + slot * 8] = v;
        }
        __syncthreads();
        // compute: wave wv owns rows [wv*16, wv*16+16)
        {
            int lrow = wv * 16 + (lane & 15);
            int lgrp = lane >> 4;
#pragma unroll
            for (int c = 0; c < 2; c++) {
                int sA = (c * 4 + lgrp) ^ (lrow & 7);
                bf16x8 a = *(bf16x8*)&As[lrow * 64 + sA * 8];
#pragma unroll
                for (int j = 0; j < 8; j++) {
                    int col = j * 16 + (lane & 15);
                    int sB = (c * 4 + lgrp) ^ (col & 7);
                    bf16x8 bfr = *(bf16x8*)&Bs[col * 64 + sB * 8];
                    acc[j] = __builtin_amdgcn_mfma_f32_16x16x32_bf16(a, bfr, acc[j], 0, 0, 0);
                }
            }
        }
        __syncthreads();
    }

    // epilogue: C layout col=lane&15, row=(lane>>4)*4+reg (m91-verified)
    const int lc = lane & 15;
#pragma unroll
    for (int j = 0; j < 8; j++) {
#pragma unroll
        for (int r = 0; r < 4; r++) {
            int lrow = wv * 16 + (lane >> 4) * 4 + r;
            int grow = block_row + lrow;
            if (grow < N) {
                float v = acc[j][r] * sdinv[lrow];
                xs[(size_t)grow * H_DIM + j * 16 + lc] = f2bf(v);
            }
        }
    }
}

// ---------------- one wave per dst row: gather-reduce (bf16 xs) + bias+relu+linear+sigmoid
__global__ __launch_bounds__(256) void gather_out_kernel(const int* __restrict__ start,
                                                         const int2* __restrict__ sedge,
                                                         const unsigned int* __restrict__ xs,
                                                         const float* __restrict__ dinv,
                                                         const float* __restrict__ b,
                                                         const float* __restrict__ Wl,
                                                         const float* __restrict__ bl,
                                                         float* __restrict__ out,
                                                         int N, int E) {
    int gw = (blockIdx.x * blockDim.x + threadIdx.x) >> 6;
    int lane = threadIdx.x & 63;
    if (gw >= N) return;
    int s0 = start[gw];
    int s1 = (gw + 1 < N) ? start[gw + 1] : E;

    unsigned int su = xs[(size_t)gw * 64 + lane];   // self-loop (already *dinv[gw])
    float ax = bf_lo(su), ay = bf_hi(su);

    for (int base = s0; base < s1; base += 64) {
        int idx = base + lane;
        int sl = 0; float wl = 0.0f;
        if (idx < s1) {
            int2 p = sedge[idx];
            sl = p.x; wl = __int_as_float(p.y);
        }
        int m = min(64, s1 - base);
        int k = 0;
        for (; k + 4 <= m; k += 4) {
            int i0 = __shfl(sl, k, 64), i1 = __shfl(sl, k + 1, 64);
            int i2 = __shfl(sl, k + 2, 64), i3 = __shfl(sl, k + 3, 64);
            float w0 = __shfl(wl, k, 64), w1 = __shfl(wl, k + 1, 64);
            float w2 = __shfl(wl, k + 2, 64), w3 = __shfl(wl, k + 3, 64);
            unsigned int u0 = xs[(size_t)i0 * 64 + lane];
            unsigned int u1 = xs[(size_t)i1 * 64 + lane];
            unsigned int u2 = xs[(size_t)i2 * 64 + lane];
            unsigned int u3 = xs[(size_t)i3 * 64 + lane];
            ax += w0 * bf_lo(u0) + w1 * bf_lo(u1) + w2 * bf_lo(u2) + w3 * bf_lo(u3);
            ay += w0 * bf_hi(u0) + w1 * bf_hi(u1) + w2 * bf_hi(u2) + w3 * bf_hi(u3);
        }
        for (; k < m; k++) {
            int i0 = __shfl(sl, k, 64);
            float w0 = __shfl(wl, k, 64);
            unsigned int u0 = xs[(size_t)i0 * 64 + lane];
            ax += w0 * bf_lo(u0);
            ay += w0 * bf_hi(u0);
        }
    }
    float di = dinv[gw];
    float2 bb = ((const float2*)b)[lane];
    float r0 = fmaxf(ax * di + bb.x, 0.0f);
    float r1 = fmaxf(ay * di + bb.y, 0.0f);
    float2 w0 = ((const float2*)Wl)[lane];
    float2 w1 = ((const float2*)(Wl + H_DIM))[lane];
    float z0 = r0 * w0.x + r1 * w0.y;
    float z1 = r0 * w1.x + r1 * w1.y;
#pragma unroll
    for (int off = 32; off; off >>= 1) {
        z0 += __shfl_xor(z0, off, 64);
        z1 += __shfl_xor(z1, off, 64);
    }
    if (lane == 0) {
        float2 o;
        o.x = 1.0f / (1.0f + expf(-(z0 + bl[0])));
        o.y = 1.0f / (1.0f + expf(-(z1 + bl[1])));
        ((float2*)out)[gw] = o;
    }
}

extern "C" void kernel_launch(void* const* d_in, const int* in_sizes, int n_in,
                              void* d_out, int out_size, void* d_ws, size_t ws_size,
                              hipStream_t stream) {
    const float* x  = (const float*)d_in[0];
    const int* ei   = (const int*)d_in[1];   // int32 on device
    const float* ew = (const float*)d_in[2];
    const float* W  = (const float*)d_in[3];
    const float* b  = (const float*)d_in[4];
    const float* Wl = (const float*)d_in[5];
    const float* bl = (const float*)d_in[6];
    float* out = (float*)d_out;

    const int N = in_sizes[0] / F_IN;   // 50000
    const int E = in_sizes[2];          // 800000
    const int nb = (N + 255) / 256;     // 196 scan blocks

    char* ws = (char*)d_ws;
    size_t off = 0;
    unsigned short* xs = (unsigned short*)(ws + off); off += (size_t)N * H_DIM * 2;      // 12.8 MB
    float* deg   = (float*)(ws + off); off += (size_t)N * 4;
    int* count   = (int*)(ws + off);   off += (size_t)N * 4;
    int* start   = (int*)(ws + off);   off += (size_t)N * 4;
    int* cursor  = (int*)(ws + off);   off += (size_t)N * 4;
    int* bsum    = (int*)(ws + off);   off += 256 * 4;
    unsigned short* Wb = (unsigned short*)(ws + off); off += (size_t)H_DIM * F_IN * 2;
    off = (off + 15) & ~(size_t)15;
    int2* sedge  = (int2*)(ws + off);  off += (size_t)E * 8;                              // 6.4 MB

    hipMemsetAsync(deg, 0, (size_t)N * 8, stream);   // deg + count adjacent

    deg_count_kernel<<<(E + 255) / 256, 256, 0, stream>>>(ei, ew, deg, count, E);
    dinv_kernel<<<(N + 255) / 256, 256, 0, stream>>>(deg, N);
    block_sum_kernel<<<nb, 256, 0, stream>>>(count, bsum, N);
    scan_bsum_kernel<<<1, 256, 0, stream>>>(bsum, nb);
    scan_write_kernel<<<nb, 256, 0, stream>>>(count, bsum, start, cursor, N);
    place_kernel<<<(E + 255) / 256, 256, 0, stream>>>(ei, ew, cursor, sedge, E);

    convw_kernel<<<(H_DIM * F_IN + 255) / 256, 256, 0, stream>>>(W, Wb, H_DIM * F_IN);
    gemm_mfma_kernel<<<(N + 63) / 64, 256, 0, stream>>>(x, Wb, deg, xs, N);

    long long gthreads = (long long)N * 64;
    gather_out_kernel<<<(int)((gthreads + 255) / 256), 256, 0, stream>>>(
        start, sedge, (const unsigned int*)xs, deg, b, Wl, bl, out, N, E);
}

// Round 5
// 157.341 us; speedup vs baseline: 9.2978x; 1.2406x over previous
//
#include <hip/hip_runtime.h>

#define F_IN 256
#define H_DIM 128

typedef short bf16x8 __attribute__((ext_vector_type(8)));
typedef float f32x4 __attribute__((ext_vector_type(4)));
typedef unsigned short ushort8 __attribute__((ext_vector_type(8)));

__device__ inline unsigned short f2bf(float f) {
    unsigned int u = __float_as_uint(f);
    u += 0x7fffu + ((u >> 16) & 1u);   // RNE
    return (unsigned short)(u >> 16);
}
__device__ inline float bf_lo(unsigned int u) { return __uint_as_float(u << 16); }
__device__ inline float bf_hi(unsigned int u) { return __uint_as_float(u & 0xffff0000u); }

// ---------------- K1: one u64 atomic per edge: hi32 = count, lo32 = fixed-point(2^16) weight sum.
// Slots padded to 64B (stride 8 u64) so line-contention == address-contention (~16x).
__global__ __launch_bounds__(256) void deg_count_kernel(const int* __restrict__ ei,
                                                        const float* __restrict__ ew,
                                                        unsigned long long* __restrict__ dc, int E) {
    int e = blockIdx.x * blockDim.x + threadIdx.x;
    if (e < E) {
        int d = ei[(size_t)E + e];
        unsigned int fx = (unsigned int)__float2uint_rn(ew[e] * 65536.0f);
        atomicAdd(&dc[(size_t)d << 3], (1ULL << 32) | (unsigned long long)fx);
    }
}

// ---------------- K2: unpack -> count (compact), dinv (compact)
__global__ __launch_bounds__(256) void unpack_kernel(const unsigned long long* __restrict__ dc,
                                                     int* __restrict__ count,
                                                     float* __restrict__ dinv, int N) {
    int i = blockIdx.x * blockDim.x + threadIdx.x;
    if (i < N) {
        unsigned long long v = dc[(size_t)i << 3];
        count[i] = (int)(v >> 32);
        float deg = (float)(unsigned int)(v & 0xffffffffu) * (1.0f / 65536.0f);
        dinv[i] = rsqrtf(deg + 1.0f);
    }
}

// ---------------- hierarchical scan: block sums
__global__ __launch_bounds__(256) void block_sum_kernel(const int* __restrict__ count,
                                                        int* __restrict__ bsum, int N) {
    __shared__ int ws[4];
    int tid = threadIdx.x, lane = tid & 63, w = tid >> 6;
    int i = blockIdx.x * 256 + tid;
    int v = (i < N) ? count[i] : 0;
#pragma unroll
    for (int off = 32; off; off >>= 1) v += __shfl_xor(v, off, 64);
    if (lane == 0) ws[w] = v;
    __syncthreads();
    if (tid == 0) bsum[blockIdx.x] = ws[0] + ws[1] + ws[2] + ws[3];
}

__global__ __launch_bounds__(256) void scan_bsum_kernel(int* __restrict__ bsum, int nb) {
    __shared__ int tmp[256];
    int tid = threadIdx.x;
    int orig = (tid < nb) ? bsum[tid] : 0;
    tmp[tid] = orig;
    __syncthreads();
    for (int off = 1; off < 256; off <<= 1) {
        int t = (tid >= off) ? tmp[tid - off] : 0;
        __syncthreads();
        tmp[tid] += t;
        __syncthreads();
    }
    if (tid < nb) bsum[tid] = tmp[tid] - orig;   // exclusive
}

// ---------------- per-block scan -> start (compact), cursor (padded 64B stride)
__global__ __launch_bounds__(256) void scan_write_kernel(const int* __restrict__ count,
                                                         const int* __restrict__ bsum,
                                                         int* __restrict__ start,
                                                         int* __restrict__ cursor, int N) {
    __shared__ int ws[4];
    int tid = threadIdx.x, lane = tid & 63, w = tid >> 6;
    int i = blockIdx.x * 256 + tid;
    int v = (i < N) ? count[i] : 0;
    int s = v;
#pragma unroll
    for (int off = 1; off < 64; off <<= 1) {
        int t = __shfl_up(s, off, 64);
        if (lane >= off) s += t;
    }
    if (lane == 63) ws[w] = s;
    __syncthreads();
    int add = bsum[blockIdx.x];
    for (int k = 0; k < w; k++) add += ws[k];
    int excl = s - v + add;
    if (i < N) { start[i] = excl; cursor[(size_t)i << 4] = excl; }
}

// ---------------- bucket edges by dst: packed (src, w_bits); cursor padded
__global__ __launch_bounds__(256) void place_kernel(const int* __restrict__ ei,
                                                    const float* __restrict__ ew,
                                                    int* __restrict__ cursor,
                                                    int2* __restrict__ sedge, int E) {
    int e = blockIdx.x * blockDim.x + threadIdx.x;
    if (e < E) {
        int s = ei[e];
        int d = ei[(size_t)E + e];
        int pos = atomicAdd(&cursor[(size_t)d << 4], 1);
        int2 p; p.x = s; p.y = __float_as_int(ew[e]);
        sedge[pos] = p;
    }
}

// ---------------- W -> bf16
__global__ __launch_bounds__(256) void convw_kernel(const float* __restrict__ W,
                                                    unsigned short* __restrict__ Wb, int n) {
    int i = blockIdx.x * blockDim.x + threadIdx.x;
    if (i < n) Wb[i] = f2bf(W[i]);
}

// ---------------- MFMA GEMM: xs(bf16) = (x @ W^T) * dinv[row]
__global__ __launch_bounds__(256) void gemm_mfma_kernel(const float* __restrict__ x,
                                                        const unsigned short* __restrict__ Wb,
                                                        const float* __restrict__ dinv,
                                                        unsigned short* __restrict__ xs, int N) {
    __shared__ unsigned short As[64 * 64];
    __shared__ unsigned short Bs[128 * 64];
    __shared__ float sdinv[64];
    const int tid = threadIdx.x;
    const int wv = tid >> 6, lane = tid & 63;
    const int block_row = blockIdx.x * 64;
    if (tid < 64) {
        int gr = block_row + tid;
        sdinv[tid] = (gr < N) ? dinv[gr] : 0.0f;
    }
    f32x4 acc[8] = {};

    for (int ks = 0; ks < 4; ks++) {
#pragma unroll
        for (int it = 0; it < 2; it++) {
            int gg = it * 256 + tid;
            int row = gg >> 3, g = gg & 7;
            int gr = block_row + row;
            float4 v0 = {0, 0, 0, 0}, v1 = {0, 0, 0, 0};
            if (gr < N) {
                const float4* p = (const float4*)&x[(size_t)gr * F_IN + ks * 64 + g * 8];
                v0 = p[0]; v1 = p[1];
            }
            ushort8 o;
            o[0] = f2bf(v0.x); o[1] = f2bf(v0.y); o[2] = f2bf(v0.z); o[3] = f2bf(v0.w);
            o[4] = f2bf(v1.x); o[5] = f2bf(v1.y); o[6] = f2bf(v1.z); o[7] = f2bf(v1.w);
            int slot = g ^ (row & 7);
            *(ushort8*)&As[row * 64 + slot * 8] = o;
        }
#pragma unroll
        for (int it = 0; it < 4; it++) {
            int gg = it * 256 + tid;
            int col = gg >> 3, g = gg & 7;
            ushort8 v = *(const ushort8*)&Wb[(size_t)col * F_IN + ks * 64 + g * 8];
            int slot = g ^ (col & 7);
            *(ushort8*)&Bs[col * 64 + slot * 8] = v;
        }
        __syncthreads();
        {
            int lrow = wv * 16 + (lane & 15);
            int lgrp = lane >> 4;
#pragma unroll
            for (int c = 0; c < 2; c++) {
                int sA = (c * 4 + lgrp) ^ (lrow & 7);
                bf16x8 a = *(bf16x8*)&As[lrow * 64 + sA * 8];
#pragma unroll
                for (int j = 0; j < 8; j++) {
                    int col = j * 16 + (lane & 15);
                    int sB = (c * 4 + lgrp) ^ (col & 7);
                    bf16x8 bfr = *(bf16x8*)&Bs[col * 64 + sB * 8];
                    acc[j] = __builtin_amdgcn_mfma_f32_16x16x32_bf16(a, bfr, acc[j], 0, 0, 0);
                }
            }
        }
        __syncthreads();
    }

    const int lc = lane & 15;
#pragma unroll
    for (int j = 0; j < 8; j++) {
#pragma unroll
        for (int r = 0; r < 4; r++) {
            int lrow = wv * 16 + (lane >> 4) * 4 + r;
            int grow = block_row + lrow;
            if (grow < N) {
                float v = acc[j][r] * sdinv[lrow];
                xs[(size_t)grow * H_DIM + j * 16 + lc] = f2bf(v);
            }
        }
    }
}

// ---------------- one wave per dst row: gather-reduce + bias+relu+linear+sigmoid
__global__ __launch_bounds__(256) void gather_out_kernel(const int* __restrict__ start,
                                                         const int2* __restrict__ sedge,
                                                         const unsigned int* __restrict__ xs,
                                                         const float* __restrict__ dinv,
                                                         const float* __restrict__ b,
                                                         const float* __restrict__ Wl,
                                                         const float* __restrict__ bl,
                                                         float* __restrict__ out,
                                                         int N, int E) {
    int gw = (blockIdx.x * blockDim.x + threadIdx.x) >> 6;
    int lane = threadIdx.x & 63;
    if (gw >= N) return;
    int s0 = start[gw];
    int s1 = (gw + 1 < N) ? start[gw + 1] : E;

    unsigned int su = xs[(size_t)gw * 64 + lane];   // self-loop (already *dinv[gw])
    float ax = bf_lo(su), ay = bf_hi(su);

    for (int base = s0; base < s1; base += 64) {
        int idx = base + lane;
        int sl = 0; float wl = 0.0f;
        if (idx < s1) {
            int2 p = sedge[idx];
            sl = p.x; wl = __int_as_float(p.y);
        }
        int m = min(64, s1 - base);
        int k = 0;
        for (; k + 4 <= m; k += 4) {
            int i0 = __shfl(sl, k, 64), i1 = __shfl(sl, k + 1, 64);
            int i2 = __shfl(sl, k + 2, 64), i3 = __shfl(sl, k + 3, 64);
            float w0 = __shfl(wl, k, 64), w1 = __shfl(wl, k + 1, 64);
            float w2 = __shfl(wl, k + 2, 64), w3 = __shfl(wl, k + 3, 64);
            unsigned int u0 = xs[(size_t)i0 * 64 + lane];
            unsigned int u1 = xs[(size_t)i1 * 64 + lane];
            unsigned int u2 = xs[(size_t)i2 * 64 + lane];
            unsigned int u3 = xs[(size_t)i3 * 64 + lane];
            ax += w0 * bf_lo(u0) + w1 * bf_lo(u1) + w2 * bf_lo(u2) + w3 * bf_lo(u3);
            ay += w0 * bf_hi(u0) + w1 * bf_hi(u1) + w2 * bf_hi(u2) + w3 * bf_hi(u3);
        }
        for (; k < m; k++) {
            int i0 = __shfl(sl, k, 64);
            float w0 = __shfl(wl, k, 64);
            unsigned int u0 = xs[(size_t)i0 * 64 + lane];
            ax += w0 * bf_lo(u0);
            ay += w0 * bf_hi(u0);
        }
    }
    float di = dinv[gw];
    float2 bb = ((const float2*)b)[lane];
    float r0 = fmaxf(ax * di + bb.x, 0.0f);
    float r1 = fmaxf(ay * di + bb.y, 0.0f);
    float2 w0 = ((const float2*)Wl)[lane];
    float2 w1 = ((const float2*)(Wl + H_DIM))[lane];
    float z0 = r0 * w0.x + r1 * w0.y;
    float z1 = r0 * w1.x + r1 * w1.y;
#pragma unroll
    for (int off = 32; off; off >>= 1) {
        z0 += __shfl_xor(z0, off, 64);
        z1 += __shfl_xor(z1, off, 64);
    }
    if (lane == 0) {
        float2 o;
        o.x = 1.0f / (1.0f + expf(-(z0 + bl[0])));
        o.y = 1.0f / (1.0f + expf(-(z1 + bl[1])));
        ((float2*)out)[gw] = o;
    }
}

extern "C" void kernel_launch(void* const* d_in, const int* in_sizes, int n_in,
                              void* d_out, int out_size, void* d_ws, size_t ws_size,
                              hipStream_t stream) {
    const float* x  = (const float*)d_in[0];
    const int* ei   = (const int*)d_in[1];   // int32 on device
    const float* ew = (const float*)d_in[2];
    const float* W  = (const float*)d_in[3];
    const float* b  = (const float*)d_in[4];
    const float* Wl = (const float*)d_in[5];
    const float* bl = (const float*)d_in[6];
    float* out = (float*)d_out;

    const int N = in_sizes[0] / F_IN;   // 50000
    const int E = in_sizes[2];          // 800000
    const int nb = (N + 255) / 256;

    char* ws = (char*)d_ws;
    size_t off = 0;
    unsigned short* xs = (unsigned short*)(ws + off); off += (size_t)N * H_DIM * 2;       // 12.8 MB
    unsigned long long* dc = (unsigned long long*)(ws + off); off += (size_t)N * 64;      // 3.2 MB padded
    int* cursor = (int*)(ws + off);  off += (size_t)N * 64;                               // 3.2 MB padded
    int* count  = (int*)(ws + off);  off += (size_t)N * 4;
    int* start  = (int*)(ws + off);  off += (size_t)N * 4;
    float* dinv = (float*)(ws + off); off += (size_t)N * 4;
    int* bsum   = (int*)(ws + off);  off += 256 * 4;
    unsigned short* Wb = (unsigned short*)(ws + off); off += (size_t)H_DIM * F_IN * 2;
    off = (off + 15) & ~(size_t)15;
    int2* sedge = (int2*)(ws + off); off += (size_t)E * 8;                                // 6.4 MB

    hipMemsetAsync(dc, 0, (size_t)N * 64, stream);

    deg_count_kernel<<<(E + 255) / 256, 256, 0, stream>>>(ei, ew, dc, E);
    unpack_kernel<<<(N + 255) / 256, 256, 0, stream>>>(dc, count, dinv, N);
    block_sum_kernel<<<nb, 256, 0, stream>>>(count, bsum, N);
    scan_bsum_kernel<<<1, 256, 0, stream>>>(bsum, nb);
    scan_write_kernel<<<nb, 256, 0, stream>>>(count, bsum, start, cursor, N);
    place_kernel<<<(E + 255) / 256, 256, 0, stream>>>(ei, ew, cursor, sedge, E);

    convw_kernel<<<(H_DIM * F_IN + 255) / 256, 256, 0, stream>>>(W, Wb, H_DIM * F_IN);
    gemm_mfma_kernel<<<(N + 63) / 64, 256, 0, stream>>>(x, Wb, dinv, xs, N);

    long long gthreads = (long long)N * 64;
    gather_out_kernel<<<(int)((gthreads + 255) / 256), 256, 0, stream>>>(
        start, sedge, (const unsigned int*)xs, dinv, b, Wl, bl, out, N, E);
}

// Round 6
// 123.812 us; speedup vs baseline: 11.8157x; 1.2708x over previous
//
#include <hip/hip_runtime.h>

#define F_IN 256
#define H_DIM 128

typedef short bf16x8 __attribute__((ext_vector_type(8)));
typedef float f32x4 __attribute__((ext_vector_type(4)));
typedef unsigned short ushort8 __attribute__((ext_vector_type(8)));

__device__ inline unsigned short f2bf(float f) {
    unsigned int u = __float_as_uint(f);
    u += 0x7fffu + ((u >> 16) & 1u);   // RNE
    return (unsigned short)(u >> 16);
}
__device__ inline float bf_lo(unsigned int u) { return __uint_as_float(u << 16); }
__device__ inline float bf_hi(unsigned int u) { return __uint_as_float(u & 0xffff0000u); }

// ---------------- K1: one u64 atomic per edge: hi32 = count, lo32 = fixed-point(2^16) weight sum.
// Padded to 64B/slot. The RETURNED hi32 is this edge's rank within its dst bucket.
__global__ __launch_bounds__(256) void deg_count_kernel(const int* __restrict__ ei,
                                                        const float* __restrict__ ew,
                                                        unsigned long long* __restrict__ dc,
                                                        int* __restrict__ rank, int E) {
    int e = blockIdx.x * blockDim.x + threadIdx.x;
    if (e < E) {
        int d = ei[(size_t)E + e];
        unsigned int fx = (unsigned int)__float2uint_rn(ew[e] * 65536.0f);
        unsigned long long old = atomicAdd(&dc[(size_t)d << 3], (1ULL << 32) | (unsigned long long)fx);
        rank[e] = (int)(old >> 32);
    }
}

// ---------------- K2: unpack -> count (compact), dinv (compact)
__global__ __launch_bounds__(256) void unpack_kernel(const unsigned long long* __restrict__ dc,
                                                     int* __restrict__ count,
                                                     float* __restrict__ dinv, int N) {
    int i = blockIdx.x * blockDim.x + threadIdx.x;
    if (i < N) {
        unsigned long long v = dc[(size_t)i << 3];
        count[i] = (int)(v >> 32);
        float deg = (float)(unsigned int)(v & 0xffffffffu) * (1.0f / 65536.0f);
        dinv[i] = rsqrtf(deg + 1.0f);
    }
}

// ---------------- hierarchical scan: block sums
__global__ __launch_bounds__(256) void block_sum_kernel(const int* __restrict__ count,
                                                        int* __restrict__ bsum, int N) {
    __shared__ int ws[4];
    int tid = threadIdx.x, lane = tid & 63, w = tid >> 6;
    int i = blockIdx.x * 256 + tid;
    int v = (i < N) ? count[i] : 0;
#pragma unroll
    for (int off = 32; off; off >>= 1) v += __shfl_xor(v, off, 64);
    if (lane == 0) ws[w] = v;
    __syncthreads();
    if (tid == 0) bsum[blockIdx.x] = ws[0] + ws[1] + ws[2] + ws[3];
}

__global__ __launch_bounds__(256) void scan_bsum_kernel(int* __restrict__ bsum, int nb) {
    __shared__ int tmp[256];
    int tid = threadIdx.x;
    int orig = (tid < nb) ? bsum[tid] : 0;
    tmp[tid] = orig;
    __syncthreads();
    for (int off = 1; off < 256; off <<= 1) {
        int t = (tid >= off) ? tmp[tid - off] : 0;
        __syncthreads();
        tmp[tid] += t;
        __syncthreads();
    }
    if (tid < nb) bsum[tid] = tmp[tid] - orig;   // exclusive
}

// ---------------- per-block scan -> start (compact)
__global__ __launch_bounds__(256) void scan_write_kernel(const int* __restrict__ count,
                                                         const int* __restrict__ bsum,
                                                         int* __restrict__ start, int N) {
    __shared__ int ws[4];
    int tid = threadIdx.x, lane = tid & 63, w = tid >> 6;
    int i = blockIdx.x * 256 + tid;
    int v = (i < N) ? count[i] : 0;
    int s = v;
#pragma unroll
    for (int off = 1; off < 64; off <<= 1) {
        int t = __shfl_up(s, off, 64);
        if (lane >= off) s += t;
    }
    if (lane == 63) ws[w] = s;
    __syncthreads();
    int add = bsum[blockIdx.x];
    for (int k = 0; k < w; k++) add += ws[k];
    int excl = s - v + add;
    if (i < N) start[i] = excl;
}

// ---------------- bucket edges by dst: pos = start[dst] + rank[e]; NO atomics
__global__ __launch_bounds__(256) void place_kernel(const int* __restrict__ ei,
                                                    const float* __restrict__ ew,
                                                    const int* __restrict__ start,
                                                    const int* __restrict__ rank,
                                                    int2* __restrict__ sedge, int E) {
    int e = blockIdx.x * blockDim.x + threadIdx.x;
    if (e < E) {
        int s = ei[e];
        int d = ei[(size_t)E + e];
        int pos = start[d] + rank[e];
        int2 p; p.x = s; p.y = __float_as_int(ew[e]);
        sedge[pos] = p;
    }
}

// ---------------- W -> bf16
__global__ __launch_bounds__(256) void convw_kernel(const float* __restrict__ W,
                                                    unsigned short* __restrict__ Wb, int n) {
    int i = blockIdx.x * blockDim.x + threadIdx.x;
    if (i < n) Wb[i] = f2bf(W[i]);
}

// ---------------- MFMA GEMM: xs(bf16) = (x @ W^T) * dinv[row]
__global__ __launch_bounds__(256) void gemm_mfma_kernel(const float* __restrict__ x,
                                                        const unsigned short* __restrict__ Wb,
                                                        const float* __restrict__ dinv,
                                                        unsigned short* __restrict__ xs, int N) {
    __shared__ unsigned short As[64 * 64];
    __shared__ unsigned short Bs[128 * 64];
    __shared__ float sdinv[64];
    const int tid = threadIdx.x;
    const int wv = tid >> 6, lane = tid & 63;
    const int block_row = blockIdx.x * 64;
    if (tid < 64) {
        int gr = block_row + tid;
        sdinv[tid] = (gr < N) ? dinv[gr] : 0.0f;
    }
    f32x4 acc[8] = {};

    for (int ks = 0; ks < 4; ks++) {
#pragma unroll
        for (int it = 0; it < 2; it++) {
            int gg = it * 256 + tid;
            int row = gg >> 3, g = gg & 7;
            int gr = block_row + row;
            float4 v0 = {0, 0, 0, 0}, v1 = {0, 0, 0, 0};
            if (gr < N) {
                const float4* p = (const float4*)&x[(size_t)gr * F_IN + ks * 64 + g * 8];
                v0 = p[0]; v1 = p[1];
            }
            ushort8 o;
            o[0] = f2bf(v0.x); o[1] = f2bf(v0.y); o[2] = f2bf(v0.z); o[3] = f2bf(v0.w);
            o[4] = f2bf(v1.x); o[5] = f2bf(v1.y); o[6] = f2bf(v1.z); o[7] = f2bf(v1.w);
            int slot = g ^ (row & 7);
            *(ushort8*)&As[row * 64 + slot * 8] = o;
        }
#pragma unroll
        for (int it = 0; it < 4; it++) {
            int gg = it * 256 + tid;
            int col = gg >> 3, g = gg & 7;
            ushort8 v = *(const ushort8*)&Wb[(size_t)col * F_IN + ks * 64 + g * 8];
            int slot = g ^ (col & 7);
            *(ushort8*)&Bs[col * 64 + slot * 8] = v;
        }
        __syncthreads();
        {
            int lrow = wv * 16 + (lane & 15);
            int lgrp = lane >> 4;
#pragma unroll
            for (int c = 0; c < 2; c++) {
                int sA = (c * 4 + lgrp) ^ (lrow & 7);
                bf16x8 a = *(bf16x8*)&As[lrow * 64 + sA * 8];
#pragma unroll
                for (int j = 0; j < 8; j++) {
                    int col = j * 16 + (lane & 15);
                    int sB = (c * 4 + lgrp) ^ (col & 7);
                    bf16x8 bfr = *(bf16x8*)&Bs[col * 64 + sB * 8];
                    acc[j] = __builtin_amdgcn_mfma_f32_16x16x32_bf16(a, bfr, acc[j], 0, 0, 0);
                }
            }
        }
        __syncthreads();
    }

    const int lc = lane & 15;
#pragma unroll
    for (int j = 0; j < 8; j++) {
#pragma unroll
        for (int r = 0; r < 4; r++) {
            int lrow = wv * 16 + (lane >> 4) * 4 + r;
            int grow = block_row + lrow;
            if (grow < N) {
                float v = acc[j][r] * sdinv[lrow];
                xs[(size_t)grow * H_DIM + j * 16 + lc] = f2bf(v);
            }
        }
    }
}

// ---------------- one wave per dst row: gather-reduce + bias+relu+linear+sigmoid
__global__ __launch_bounds__(256) void gather_out_kernel(const int* __restrict__ start,
                                                         const int2* __restrict__ sedge,
                                                         const unsigned int* __restrict__ xs,
                                                         const float* __restrict__ dinv,
                                                         const float* __restrict__ b,
                                                         const float* __restrict__ Wl,
                                                         const float* __restrict__ bl,
                                                         float* __restrict__ out,
                                                         int N, int E) {
    int gw = (blockIdx.x * blockDim.x + threadIdx.x) >> 6;
    int lane = threadIdx.x & 63;
    if (gw >= N) return;
    int s0 = start[gw];
    int s1 = (gw + 1 < N) ? start[gw + 1] : E;

    unsigned int su = xs[(size_t)gw * 64 + lane];   // self-loop (already *dinv[gw])
    float ax = bf_lo(su), ay = bf_hi(su);

    for (int base = s0; base < s1; base += 64) {
        int idx = base + lane;
        int sl = 0; float wl = 0.0f;
        if (idx < s1) {
            int2 p = sedge[idx];
            sl = p.x; wl = __int_as_float(p.y);
        }
        int m = min(64, s1 - base);
        int k = 0;
        for (; k + 8 <= m; k += 8) {
            int i0 = __shfl(sl, k, 64),     i1 = __shfl(sl, k + 1, 64);
            int i2 = __shfl(sl, k + 2, 64), i3 = __shfl(sl, k + 3, 64);
            int i4 = __shfl(sl, k + 4, 64), i5 = __shfl(sl, k + 5, 64);
            int i6 = __shfl(sl, k + 6, 64), i7 = __shfl(sl, k + 7, 64);
            float w0 = __shfl(wl, k, 64),     w1 = __shfl(wl, k + 1, 64);
            float w2 = __shfl(wl, k + 2, 64), w3 = __shfl(wl, k + 3, 64);
            float w4 = __shfl(wl, k + 4, 64), w5 = __shfl(wl, k + 5, 64);
            float w6 = __shfl(wl, k + 6, 64), w7 = __shfl(wl, k + 7, 64);
            unsigned int u0 = xs[(size_t)i0 * 64 + lane];
            unsigned int u1 = xs[(size_t)i1 * 64 + lane];
            unsigned int u2 = xs[(size_t)i2 * 64 + lane];
            unsigned int u3 = xs[(size_t)i3 * 64 + lane];
            unsigned int u4 = xs[(size_t)i4 * 64 + lane];
            unsigned int u5 = xs[(size_t)i5 * 64 + lane];
            unsigned int u6 = xs[(size_t)i6 * 64 + lane];
            unsigned int u7 = xs[(size_t)i7 * 64 + lane];
            ax += w0 * bf_lo(u0) + w1 * bf_lo(u1) + w2 * bf_lo(u2) + w3 * bf_lo(u3)
                + w4 * bf_lo(u4) + w5 * bf_lo(u5) + w6 * bf_lo(u6) + w7 * bf_lo(u7);
            ay += w0 * bf_hi(u0) + w1 * bf_hi(u1) + w2 * bf_hi(u2) + w3 * bf_hi(u3)
                + w4 * bf_hi(u4) + w5 * bf_hi(u5) + w6 * bf_hi(u6) + w7 * bf_hi(u7);
        }
        for (; k < m; k++) {
            int i0 = __shfl(sl, k, 64);
            float w0 = __shfl(wl, k, 64);
            unsigned int u0 = xs[(size_t)i0 * 64 + lane];
            ax += w0 * bf_lo(u0);
            ay += w0 * bf_hi(u0);
        }
    }
    float di = dinv[gw];
    float2 bb = ((const float2*)b)[lane];
    float r0 = fmaxf(ax * di + bb.x, 0.0f);
    float r1 = fmaxf(ay * di + bb.y, 0.0f);
    float2 w0 = ((const float2*)Wl)[lane];
    float2 w1 = ((const float2*)(Wl + H_DIM))[lane];
    float z0 = r0 * w0.x + r1 * w0.y;
    float z1 = r0 * w1.x + r1 * w1.y;
#pragma unroll
    for (int off = 32; off; off >>= 1) {
        z0 += __shfl_xor(z0, off, 64);
        z1 += __shfl_xor(z1, off, 64);
    }
    if (lane == 0) {
        float2 o;
        o.x = 1.0f / (1.0f + expf(-(z0 + bl[0])));
        o.y = 1.0f / (1.0f + expf(-(z1 + bl[1])));
        ((float2*)out)[gw] = o;
    }
}

extern "C" void kernel_launch(void* const* d_in, const int* in_sizes, int n_in,
                              void* d_out, int out_size, void* d_ws, size_t ws_size,
                              hipStream_t stream) {
    const float* x  = (const float*)d_in[0];
    const int* ei   = (const int*)d_in[1];   // int32 on device
    const float* ew = (const float*)d_in[2];
    const float* W  = (const float*)d_in[3];
    const float* b  = (const float*)d_in[4];
    const float* Wl = (const float*)d_in[5];
    const float* bl = (const float*)d_in[6];
    float* out = (float*)d_out;

    const int N = in_sizes[0] / F_IN;   // 50000
    const int E = in_sizes[2];          // 800000
    const int nb = (N + 255) / 256;

    char* ws = (char*)d_ws;
    size_t off = 0;
    unsigned short* xs = (unsigned short*)(ws + off); off += (size_t)N * H_DIM * 2;       // 12.8 MB
    unsigned long long* dc = (unsigned long long*)(ws + off); off += (size_t)N * 64;      // 3.2 MB padded
    int* rank   = (int*)(ws + off);  off += (size_t)E * 4;                                // 3.2 MB
    int* count  = (int*)(ws + off);  off += (size_t)N * 4;
    int* start  = (int*)(ws + off);  off += (size_t)N * 4;
    float* dinv = (float*)(ws + off); off += (size_t)N * 4;
    int* bsum   = (int*)(ws + off);  off += 256 * 4;
    unsigned short* Wb = (unsigned short*)(ws + off); off += (size_t)H_DIM * F_IN * 2;
    off = (off + 15) & ~(size_t)15;
    int2* sedge = (int2*)(ws + off); off += (size_t)E * 8;                                // 6.4 MB

    hipMemsetAsync(dc, 0, (size_t)N * 64, stream);

    deg_count_kernel<<<(E + 255) / 256, 256, 0, stream>>>(ei, ew, dc, rank, E);
    unpack_kernel<<<(N + 255) / 256, 256, 0, stream>>>(dc, count, dinv, N);
    block_sum_kernel<<<nb, 256, 0, stream>>>(count, bsum, N);
    scan_bsum_kernel<<<1, 256, 0, stream>>>(bsum, nb);
    scan_write_kernel<<<nb, 256, 0, stream>>>(count, bsum, start, N);
    place_kernel<<<(E + 255) / 256, 256, 0, stream>>>(ei, ew, start, rank, sedge, E);

    convw_kernel<<<(H_DIM * F_IN + 255) / 256, 256, 0, stream>>>(W, Wb, H_DIM * F_IN);
    gemm_mfma_kernel<<<(N + 63) / 64, 256, 0, stream>>>(x, Wb, dinv, xs, N);

    long long gthreads = (long long)N * 64;
    gather_out_kernel<<<(int)((gthreads + 255) / 256), 256, 0, stream>>>(
        start, sedge, (const unsigned int*)xs, dinv, b, Wl, bl, out, N, E);
}

// Round 7
// 122.113 us; speedup vs baseline: 11.9801x; 1.0139x over previous
//
#include <hip/hip_runtime.h>

#define F_IN 256
#define H_DIM 128

typedef short bf16x8 __attribute__((ext_vector_type(8)));
typedef float f32x4 __attribute__((ext_vector_type(4)));
typedef unsigned short ushort8 __attribute__((ext_vector_type(8)));

__device__ inline unsigned short f2bf(float f) {
    unsigned int u = __float_as_uint(f);
    u += 0x7fffu + ((u >> 16) & 1u);   // RNE
    return (unsigned short)(u >> 16);
}
__device__ inline float bf_lo(unsigned int u) { return __uint_as_float(u << 16); }
__device__ inline float bf_hi(unsigned int u) { return __uint_as_float(u & 0xffff0000u); }

// ---------------- K0: zero only the used 8B of each 64B-padded dc slot
__global__ __launch_bounds__(256) void zero_dc_kernel(unsigned long long* __restrict__ dc, int N) {
    int i = blockIdx.x * blockDim.x + threadIdx.x;
    if (i < N) dc[(size_t)i << 3] = 0ULL;
}

// ---------------- K1: one u64 atomic per edge: hi32 = count, lo32 = fixed-point(2^16) weight sum.
// Padded to 64B/slot. The RETURNED hi32 is this edge's rank within its dst bucket.
__global__ __launch_bounds__(256) void deg_count_kernel(const int* __restrict__ ei,
                                                        const float* __restrict__ ew,
                                                        unsigned long long* __restrict__ dc,
                                                        int* __restrict__ rank, int E) {
    int e = blockIdx.x * blockDim.x + threadIdx.x;
    if (e < E) {
        int d = ei[(size_t)E + e];
        unsigned int fx = (unsigned int)__float2uint_rn(ew[e] * 65536.0f);
        unsigned long long old = atomicAdd(&dc[(size_t)d << 3], (1ULL << 32) | (unsigned long long)fx);
        rank[e] = (int)(old >> 32);
    }
}

// ---------------- K2: unpack -> count, dinv; fused per-block sum -> bsum
__global__ __launch_bounds__(256) void unpack_bsum_kernel(const unsigned long long* __restrict__ dc,
                                                          int* __restrict__ count,
                                                          float* __restrict__ dinv,
                                                          int* __restrict__ bsum, int N) {
    __shared__ int ws[4];
    int tid = threadIdx.x, lane = tid & 63, w = tid >> 6;
    int i = blockIdx.x * 256 + tid;
    int c = 0;
    if (i < N) {
        unsigned long long v = dc[(size_t)i << 3];
        c = (int)(v >> 32);
        count[i] = c;
        float deg = (float)(unsigned int)(v & 0xffffffffu) * (1.0f / 65536.0f);
        dinv[i] = rsqrtf(deg + 1.0f);
    }
    int v = c;
#pragma unroll
    for (int off = 32; off; off >>= 1) v += __shfl_xor(v, off, 64);
    if (lane == 0) ws[w] = v;
    __syncthreads();
    if (tid == 0) bsum[blockIdx.x] = ws[0] + ws[1] + ws[2] + ws[3];
}

__global__ __launch_bounds__(256) void scan_bsum_kernel(int* __restrict__ bsum, int nb) {
    __shared__ int tmp[256];
    int tid = threadIdx.x;
    int orig = (tid < nb) ? bsum[tid] : 0;
    tmp[tid] = orig;
    __syncthreads();
    for (int off = 1; off < 256; off <<= 1) {
        int t = (tid >= off) ? tmp[tid - off] : 0;
        __syncthreads();
        tmp[tid] += t;
        __syncthreads();
    }
    if (tid < nb) bsum[tid] = tmp[tid] - orig;   // exclusive
}

// ---------------- per-block scan -> start (compact)
__global__ __launch_bounds__(256) void scan_write_kernel(const int* __restrict__ count,
                                                         const int* __restrict__ bsum,
                                                         int* __restrict__ start, int N) {
    __shared__ int ws[4];
    int tid = threadIdx.x, lane = tid & 63, w = tid >> 6;
    int i = blockIdx.x * 256 + tid;
    int v = (i < N) ? count[i] : 0;
    int s = v;
#pragma unroll
    for (int off = 1; off < 64; off <<= 1) {
        int t = __shfl_up(s, off, 64);
        if (lane >= off) s += t;
    }
    if (lane == 63) ws[w] = s;
    __syncthreads();
    int add = bsum[blockIdx.x];
    for (int k = 0; k < w; k++) add += ws[k];
    int excl = s - v + add;
    if (i < N) start[i] = excl;
}

// ---------------- bucket edges by dst: pos = start[dst] + rank[e]; NO atomics
__global__ __launch_bounds__(256) void place_kernel(const int* __restrict__ ei,
                                                    const float* __restrict__ ew,
                                                    const int* __restrict__ start,
                                                    const int* __restrict__ rank,
                                                    int2* __restrict__ sedge, int E) {
    int e = blockIdx.x * blockDim.x + threadIdx.x;
    if (e < E) {
        int s = ei[e];
        int d = ei[(size_t)E + e];
        int pos = start[d] + rank[e];
        int2 p; p.x = s; p.y = __float_as_int(ew[e]);
        sedge[pos] = p;
    }
}

// ---------------- W -> bf16
__global__ __launch_bounds__(256) void convw_kernel(const float* __restrict__ W,
                                                    unsigned short* __restrict__ Wb, int n) {
    int i = blockIdx.x * blockDim.x + threadIdx.x;
    if (i < n) Wb[i] = f2bf(W[i]);
}

// ---------------- MFMA GEMM: xs(bf16) = (x @ W^T) * dinv[row]
__global__ __launch_bounds__(256) void gemm_mfma_kernel(const float* __restrict__ x,
                                                        const unsigned short* __restrict__ Wb,
                                                        const float* __restrict__ dinv,
                                                        unsigned short* __restrict__ xs, int N) {
    __shared__ unsigned short As[64 * 64];
    __shared__ unsigned short Bs[128 * 64];
    __shared__ float sdinv[64];
    const int tid = threadIdx.x;
    const int wv = tid >> 6, lane = tid & 63;
    const int block_row = blockIdx.x * 64;
    if (tid < 64) {
        int gr = block_row + tid;
        sdinv[tid] = (gr < N) ? dinv[gr] : 0.0f;
    }
    f32x4 acc[8] = {};

    for (int ks = 0; ks < 4; ks++) {
#pragma unroll
        for (int it = 0; it < 2; it++) {
            int gg = it * 256 + tid;
            int row = gg >> 3, g = gg & 7;
            int gr = block_row + row;
            float4 v0 = {0, 0, 0, 0}, v1 = {0, 0, 0, 0};
            if (gr < N) {
                const float4* p = (const float4*)&x[(size_t)gr * F_IN + ks * 64 + g * 8];
                v0 = p[0]; v1 = p[1];
            }
            ushort8 o;
            o[0] = f2bf(v0.x); o[1] = f2bf(v0.y); o[2] = f2bf(v0.z); o[3] = f2bf(v0.w);
            o[4] = f2bf(v1.x); o[5] = f2bf(v1.y); o[6] = f2bf(v1.z); o[7] = f2bf(v1.w);
            int slot = g ^ (row & 7);
            *(ushort8*)&As[row * 64 + slot * 8] = o;
        }
#pragma unroll
        for (int it = 0; it < 4; it++) {
            int gg = it * 256 + tid;
            int col = gg >> 3, g = gg & 7;
            ushort8 v = *(const ushort8*)&Wb[(size_t)col * F_IN + ks * 64 + g * 8];
            int slot = g ^ (col & 7);
            *(ushort8*)&Bs[col * 64 + slot * 8] = v;
        }
        __syncthreads();
        {
            int lrow = wv * 16 + (lane & 15);
            int lgrp = lane >> 4;
#pragma unroll
            for (int c = 0; c < 2; c++) {
                int sA = (c * 4 + lgrp) ^ (lrow & 7);
                bf16x8 a = *(bf16x8*)&As[lrow * 64 + sA * 8];
#pragma unroll
                for (int j = 0; j < 8; j++) {
                    int col = j * 16 + (lane & 15);
                    int sB = (c * 4 + lgrp) ^ (col & 7);
                    bf16x8 bfr = *(bf16x8*)&Bs[col * 64 + sB * 8];
                    acc[j] = __builtin_amdgcn_mfma_f32_16x16x32_bf16(a, bfr, acc[j], 0, 0, 0);
                }
            }
        }
        __syncthreads();
    }

    const int lc = lane & 15;
#pragma unroll
    for (int j = 0; j < 8; j++) {
#pragma unroll
        for (int r = 0; r < 4; r++) {
            int lrow = wv * 16 + (lane >> 4) * 4 + r;
            int grow = block_row + lrow;
            if (grow < N) {
                float v = acc[j][r] * sdinv[lrow];
                xs[(size_t)grow * H_DIM + j * 16 + lc] = f2bf(v);
            }
        }
    }
}

// ---------------- one wave per dst row: gather-reduce + bias+relu+linear+sigmoid
__global__ __launch_bounds__(256) void gather_out_kernel(const int* __restrict__ start,
                                                         const int2* __restrict__ sedge,
                                                         const unsigned int* __restrict__ xs,
                                                         const float* __restrict__ dinv,
                                                         const float* __restrict__ b,
                                                         const float* __restrict__ Wl,
                                                         const float* __restrict__ bl,
                                                         float* __restrict__ out,
                                                         int N, int E) {
    int gw = (blockIdx.x * blockDim.x + threadIdx.x) >> 6;
    int lane = threadIdx.x & 63;
    if (gw >= N) return;
    int s0 = start[gw];
    int s1 = (gw + 1 < N) ? start[gw + 1] : E;

    unsigned int su = xs[(size_t)gw * 64 + lane];   // self-loop (already *dinv[gw])
    float ax = bf_lo(su), ay = bf_hi(su);

    for (int base = s0; base < s1; base += 64) {
        int idx = base + lane;
        int sl = 0; float wl = 0.0f;
        if (idx < s1) {
            int2 p = sedge[idx];
            sl = p.x; wl = __int_as_float(p.y);
        }
        int m = min(64, s1 - base);
        int k = 0;
        for (; k + 8 <= m; k += 8) {
            int i0 = __shfl(sl, k, 64),     i1 = __shfl(sl, k + 1, 64);
            int i2 = __shfl(sl, k + 2, 64), i3 = __shfl(sl, k + 3, 64);
            int i4 = __shfl(sl, k + 4, 64), i5 = __shfl(sl, k + 5, 64);
            int i6 = __shfl(sl, k + 6, 64), i7 = __shfl(sl, k + 7, 64);
            float w0 = __shfl(wl, k, 64),     w1 = __shfl(wl, k + 1, 64);
            float w2 = __shfl(wl, k + 2, 64), w3 = __shfl(wl, k + 3, 64);
            float w4 = __shfl(wl, k + 4, 64), w5 = __shfl(wl, k + 5, 64);
            float w6 = __shfl(wl, k + 6, 64), w7 = __shfl(wl, k + 7, 64);
            unsigned int u0 = xs[(size_t)i0 * 64 + lane];
            unsigned int u1 = xs[(size_t)i1 * 64 + lane];
            unsigned int u2 = xs[(size_t)i2 * 64 + lane];
            unsigned int u3 = xs[(size_t)i3 * 64 + lane];
            unsigned int u4 = xs[(size_t)i4 * 64 + lane];
            unsigned int u5 = xs[(size_t)i5 * 64 + lane];
            unsigned int u6 = xs[(size_t)i6 * 64 + lane];
            unsigned int u7 = xs[(size_t)i7 * 64 + lane];
            ax += w0 * bf_lo(u0) + w1 * bf_lo(u1) + w2 * bf_lo(u2) + w3 * bf_lo(u3)
                + w4 * bf_lo(u4) + w5 * bf_lo(u5) + w6 * bf_lo(u6) + w7 * bf_lo(u7);
            ay += w0 * bf_hi(u0) + w1 * bf_hi(u1) + w2 * bf_hi(u2) + w3 * bf_hi(u3)
                + w4 * bf_hi(u4) + w5 * bf_hi(u5) + w6 * bf_hi(u6) + w7 * bf_hi(u7);
        }
        for (; k < m; k++) {
            int i0 = __shfl(sl, k, 64);
            float w0 = __shfl(wl, k, 64);
            unsigned int u0 = xs[(size_t)i0 * 64 + lane];
            ax += w0 * bf_lo(u0);
            ay += w0 * bf_hi(u0);
        }
    }
    float di = dinv[gw];
    float2 bb = ((const float2*)b)[lane];
    float r0 = fmaxf(ax * di + bb.x, 0.0f);
    float r1 = fmaxf(ay * di + bb.y, 0.0f);
    float2 w0 = ((const float2*)Wl)[lane];
    float2 w1 = ((const float2*)(Wl + H_DIM))[lane];
    float z0 = r0 * w0.x + r1 * w0.y;
    float z1 = r0 * w1.x + r1 * w1.y;
#pragma unroll
    for (int off = 32; off; off >>= 1) {
        z0 += __shfl_xor(z0, off, 64);
        z1 += __shfl_xor(z1, off, 64);
    }
    if (lane == 0) {
        float2 o;
        o.x = 1.0f / (1.0f + expf(-(z0 + bl[0])));
        o.y = 1.0f / (1.0f + expf(-(z1 + bl[1])));
        ((float2*)out)[gw] = o;
    }
}

extern "C" void kernel_launch(void* const* d_in, const int* in_sizes, int n_in,
                              void* d_out, int out_size, void* d_ws, size_t ws_size,
                              hipStream_t stream) {
    const float* x  = (const float*)d_in[0];
    const int* ei   = (const int*)d_in[1];   // int32 on device
    const float* ew = (const float*)d_in[2];
    const float* W  = (const float*)d_in[3];
    const float* b  = (const float*)d_in[4];
    const float* Wl = (const float*)d_in[5];
    const float* bl = (const float*)d_in[6];
    float* out = (float*)d_out;

    const int N = in_sizes[0] / F_IN;   // 50000
    const int E = in_sizes[2];          // 800000
    const int nb = (N + 255) / 256;

    char* ws = (char*)d_ws;
    size_t off = 0;
    unsigned short* xs = (unsigned short*)(ws + off); off += (size_t)N * H_DIM * 2;       // 12.8 MB
    unsigned long long* dc = (unsigned long long*)(ws + off); off += (size_t)N * 64;      // 3.2 MB padded
    int* rank   = (int*)(ws + off);  off += (size_t)E * 4;                                // 3.2 MB
    int* count  = (int*)(ws + off);  off += (size_t)N * 4;
    int* start  = (int*)(ws + off);  off += (size_t)N * 4;
    float* dinv = (float*)(ws + off); off += (size_t)N * 4;
    int* bsum   = (int*)(ws + off);  off += 256 * 4;
    unsigned short* Wb = (unsigned short*)(ws + off); off += (size_t)H_DIM * F_IN * 2;
    off = (off + 15) & ~(size_t)15;
    int2* sedge = (int2*)(ws + off); off += (size_t)E * 8;                                // 6.4 MB

    zero_dc_kernel<<<nb, 256, 0, stream>>>(dc, N);
    deg_count_kernel<<<(E + 255) / 256, 256, 0, stream>>>(ei, ew, dc, rank, E);
    unpack_bsum_kernel<<<nb, 256, 0, stream>>>(dc, count, dinv, bsum, N);
    scan_bsum_kernel<<<1, 256, 0, stream>>>(bsum, nb);
    scan_write_kernel<<<nb, 256, 0, stream>>>(count, bsum, start, N);
    place_kernel<<<(E + 255) / 256, 256, 0, stream>>>(ei, ew, start, rank, sedge, E);

    convw_kernel<<<(H_DIM * F_IN + 255) / 256, 256, 0, stream>>>(W, Wb, H_DIM * F_IN);
    gemm_mfma_kernel<<<(N + 63) / 64, 256, 0, stream>>>(x, Wb, dinv, xs, N);

    long long gthreads = (long long)N * 64;
    gather_out_kernel<<<(int)((gthreads + 255) / 256), 256, 0, stream>>>(
        start, sedge, (const unsigned int*)xs, dinv, b, Wl, bl, out, N, E);
}